// Round 1
// baseline (1203.590 us; speedup 1.0000x reference)
//
#include <hip/hip_runtime.h>
#include <hip/hip_bf16.h>
#include <stdint.h>

// NNUE bucket model R4: software-pipelined GEMMs (T3 minimum 2-phase).
//   K3/K4: double-buffered LDS; stage tile t+1 (gl_lds B + reg-convert A)
//   BEFORE computing tile t; single __syncthreads per k-iter (its internal
//   vmcnt(0)+lgkmcnt(0) drain now lands AFTER the MFMA block, so global-load
//   latency hides under compute instead of serializing ahead of it).
//   A-path uses a depth-2 register prefetch (load t+2 during iter t).
//   R3 heritage: convert_x fused into gemm_ft, chunk-XOR LDS swizzle
//   (conflicts = 0), XCD-paired m-tiles for the 2nd fp32 A read.

#define INF  770
#define XROW 1540
#define KP   800
#define FT   512
#define K2   1024
#define N2   256

typedef _Float16 half8 __attribute__((ext_vector_type(8)));
typedef float floatx4 __attribute__((ext_vector_type(4)));
typedef float floatx2 __attribute__((ext_vector_type(2)));

__device__ __forceinline__ float crelu_f(float v) {
    return v < 0.f ? 0.f : (v > 1.f ? 1.f : v);
}

__device__ __forceinline__ void gl_lds16(const _Float16* g, _Float16* l) {
    __builtin_amdgcn_global_load_lds(
        (__attribute__((address_space(1))) void*)(uintptr_t)(const void*)g,
        (__attribute__((address_space(3))) void*)l,
        16, 0, 0);
}

// ---------------- K2: convert weights ----------------
__global__ __launch_bounds__(256) void convert_w_kernel(
    const float* __restrict__ ftw, const float* __restrict__ h1w,
    _Float16* __restrict__ ftw16, _Float16* __restrict__ h1w16)
{
    int idx = blockIdx.x * 256 + threadIdx.x;
    const int FTW = FT * KP;            // 409600
    if (idx < FTW) {
        int r = idx / KP, c = idx - r * KP;
        ftw16[idx] = (_Float16)(c < INF ? ftw[r * INF + c] : 0.f);
    } else {
        int j = idx - FTW;
        if (j < N2 * K2) h1w16[j] = (_Float16)h1w[j];
    }
}

// ---------------- K3: fused FT GEMM (pipelined) ----------------
__global__ __launch_bounds__(512, 4) void gemm_ft_fused(
    const float* __restrict__ x,      // (B, 1540)
    const _Float16* __restrict__ Bt,  // (512, 800) padded fp16
    const float* __restrict__ bias,   // (512)
    _Float16* __restrict__ C,         // (2B, 512)
    int* __restrict__ bucket, int B)
{
    __shared__ _Float16 lsA[2][128 * 32];   // 16 KB
    __shared__ _Float16 lsB[2][256 * 32];   // 32 KB
    // XCD pairing: bid%8 = XCD; the 2 n-blocks of an m-tile run adjacent on
    // one XCD so the 2nd read of the fp32 A-tile (788 KB) hits that L2.
    int bid = blockIdx.x;
    int xcd = bid & 7, g = bid >> 3;
    int nt = g & 1, mt = (g >> 1) * 8 + xcd;      // mt in [0,1024)
    int m0 = mt * 128, n0 = nt * 256;
    int tid = threadIdx.x, lane = tid & 63, w = tid >> 6;
    int rm = (w & 1) * 64, rn = (w >> 1) * 64;
    int colL = lane & 15, rowQ = lane >> 4;
    int chA = rowQ ^ ((colL >> 1) & 3);

    // A staging identity: thread -> (row, 16B chunk kq)
    int arow = tid >> 2, kq = tid & 3;
    const float* asrc = (m0 < B)
        ? x + (size_t)(m0 + arow) * XROW
        : x + (size_t)(m0 - B + arow) * XROW + INF;
    int aoff = arow * 32 + (kq ^ ((arow >> 1) & 3)) * 8;

    floatx4 acc[4][4] = {};
    float psum = 0.f;
    floatx2 f0, f1, f2, f3, ae = {};

    // ---- prologue: stage tile 0 into buf0, prefetch A regs for tile 1 ----
    {
        const float* pp = asrc + kq * 8;
        f0 = *(const floatx2*)(pp);
        f1 = *(const floatx2*)(pp + 2);
        f2 = *(const floatx2*)(pp + 4);
        f3 = *(const floatx2*)(pp + 6);
    }
    #pragma unroll
    for (int q = 0; q < 2; ++q) {
        int idx = q * 512 + tid;
        int br = idx >> 2, bs = (idx & 3) ^ ((br >> 1) & 3);
        gl_lds16(Bt + (size_t)(n0 + br) * KP + bs * 8, lsB[0] + idx * 8);
    }
    {
        half8 hv;
        hv[0] = (_Float16)f0.x; hv[1] = (_Float16)f0.y;
        hv[2] = (_Float16)f1.x; hv[3] = (_Float16)f1.y;
        hv[4] = (_Float16)f2.x; hv[5] = (_Float16)f2.y;
        hv[6] = (_Float16)f3.x; hv[7] = (_Float16)f3.y;
        psum += (f0.x + f0.y) + (f1.x + f1.y) + (f2.x + f2.y) + (f3.x + f3.y);
        *(half8*)(lsA[0] + aoff) = hv;
    }
    {
        const float* pp = asrc + 32 + kq * 8;
        f0 = *(const floatx2*)(pp);
        f1 = *(const floatx2*)(pp + 2);
        f2 = *(const floatx2*)(pp + 4);
        f3 = *(const floatx2*)(pp + 6);
    }
    __syncthreads();   // internal vmcnt(0)+lgkmcnt(0): buf0 ready

    int p = 0;
    for (int t = 0; t < 25; ++t) {
        if (t < 24) {
            // ---- stage tile t+1 into buf p^1 (issue-early, drain at barrier) ----
            int ks = (t + 1) * 32;
            #pragma unroll
            for (int q = 0; q < 2; ++q) {
                int idx = q * 512 + tid;
                int br = idx >> 2, bs = (idx & 3) ^ ((br >> 1) & 3);
                gl_lds16(Bt + (size_t)(n0 + br) * KP + ks + bs * 8,
                         lsB[p ^ 1] + idx * 8);
            }
            // A tile t+1: regs were prefetched last iter -> convert -> LDS
            half8 hv = {};
            if (t < 23) {
                hv[0] = (_Float16)f0.x; hv[1] = (_Float16)f0.y;
                hv[2] = (_Float16)f1.x; hv[3] = (_Float16)f1.y;
                hv[4] = (_Float16)f2.x; hv[5] = (_Float16)f2.y;
                hv[6] = (_Float16)f3.x; hv[7] = (_Float16)f3.y;
                psum += (f0.x + f0.y) + (f1.x + f1.y) + (f2.x + f2.y) + (f3.x + f3.y);
            } else if (kq == 0) {
                // tile 24: k = 768,769 real; rest zero pad
                hv[0] = (_Float16)ae.x; hv[1] = (_Float16)ae.y;
            }
            *(half8*)(lsA[p ^ 1] + aoff) = hv;
            // prefetch A regs for tile t+2
            if (t < 22) {
                const float* pp = asrc + (t + 2) * 32 + kq * 8;
                f0 = *(const floatx2*)(pp);
                f1 = *(const floatx2*)(pp + 2);
                f2 = *(const floatx2*)(pp + 4);
                f3 = *(const floatx2*)(pp + 6);
            } else if (t == 22) {
                if (kq == 0) ae = *(const floatx2*)(asrc + 768);
            }
        }
        // ---- compute tile t from buf p ----
        half8 af[4], bf[4];
        #pragma unroll
        for (int i = 0; i < 4; ++i)
            af[i] = *(const half8*)(lsA[p] + (rm + i * 16 + colL) * 32 + chA * 8);
        #pragma unroll
        for (int j = 0; j < 4; ++j)
            bf[j] = *(const half8*)(lsB[p] + (rn + j * 16 + colL) * 32 + chA * 8);
        __builtin_amdgcn_s_setprio(1);
        #pragma unroll
        for (int i = 0; i < 4; ++i)
            #pragma unroll
            for (int j = 0; j < 4; ++j)
                acc[i][j] = __builtin_amdgcn_mfma_f32_16x16x32_f16(af[i], bf[j], acc[i][j], 0, 0, 0);
        __builtin_amdgcn_s_setprio(0);
        if (t < 24) { __syncthreads(); p ^= 1; }
    }

    // ---- bucket (pc = sum x[:, :768], exactly the 24 full tiles) ----
    psum += __shfl_xor(psum, 1, 64);
    psum += __shfl_xor(psum, 2, 64);
    if (nt == 0 && m0 < B && (tid & 3) == 0) {
        int bk = (int)(psum * (8.0f / 33.0f));
        bucket[m0 + arow] = bk < 0 ? 0 : (bk > 7 ? 7 : bk);
    }

    // ---- epilogue ----
    #pragma unroll
    for (int j = 0; j < 4; ++j) {
        int gn = n0 + rn + j * 16 + colL;
        float bv = bias[gn];
        #pragma unroll
        for (int i = 0; i < 4; ++i) {
            #pragma unroll
            for (int r = 0; r < 4; ++r) {
                int gm = m0 + rm + i * 16 + rowQ * 4 + r;
                C[(size_t)gm * FT + gn] = (_Float16)crelu_f(acc[i][j][r] + bv);
            }
        }
    }
}

// ---------------- K4: h1 GEMM (pipelined, full-N blocks) ----------------
__global__ __launch_bounds__(512, 4) void gemm_h1_kernel(
    const _Float16* __restrict__ C1,  // (2B, 512)
    const _Float16* __restrict__ Bt,  // (256, 1024)
    const float* __restrict__ bias,   // (256)
    float* __restrict__ H,            // (B, 256)
    int B)
{
    __shared__ _Float16 lsA[2][64 * 32];    // 8 KB
    __shared__ _Float16 lsB[2][256 * 32];   // 32 KB
    int m0 = blockIdx.x * 64;
    int tid = threadIdx.x, lane = tid & 63, w = tid >> 6;   // 8 waves: n-slice 32 each
    int colL = lane & 15, rowQ = lane >> 4;
    int chA = rowQ ^ ((colL >> 1) & 3);

    floatx4 acc[4][2] = {};

    auto stage = [&](int kt, int b) {
        int ks = kt * 32;
        // combined[m][k] = k<512 ? C1[m][k] : C1[B+m][k-512]
        const _Float16* Abase = (ks < FT) ? (C1 + (size_t)m0 * FT + ks)
                                          : (C1 + (size_t)(B + m0) * FT + (ks - FT));
        if (tid < 256) {   // waves 0-3 stage A (2 KB)
            int br = tid >> 2, bs = (tid & 3) ^ ((br >> 1) & 3);
            gl_lds16(Abase + (size_t)br * FT + bs * 8, lsA[b] + tid * 8);
        }
        #pragma unroll
        for (int q = 0; q < 2; ++q) {
            int idx = q * 512 + tid;
            int br = idx >> 2, bs = (idx & 3) ^ ((br >> 1) & 3);
            gl_lds16(Bt + (size_t)br * K2 + ks + bs * 8, lsB[b] + idx * 8);
        }
    };

    stage(0, 0);
    __syncthreads();

    int p = 0;
    for (int t = 0; t < 32; ++t) {
        if (t < 31) stage(t + 1, p ^ 1);     // issue-early
        half8 af[4], bf[2];
        #pragma unroll
        for (int i = 0; i < 4; ++i)
            af[i] = *(const half8*)(lsA[p] + (i * 16 + colL) * 32 + chA * 8);
        #pragma unroll
        for (int j = 0; j < 2; ++j)
            bf[j] = *(const half8*)(lsB[p] + (w * 32 + j * 16 + colL) * 32 + chA * 8);
        __builtin_amdgcn_s_setprio(1);
        #pragma unroll
        for (int i = 0; i < 4; ++i)
            #pragma unroll
            for (int j = 0; j < 2; ++j)
                acc[i][j] = __builtin_amdgcn_mfma_f32_16x16x32_f16(af[i], bf[j], acc[i][j], 0, 0, 0);
        __builtin_amdgcn_s_setprio(0);
        if (t < 31) { __syncthreads(); p ^= 1; }
    }

    #pragma unroll
    for (int j = 0; j < 2; ++j) {
        int gn = w * 32 + j * 16 + colL;
        float bv = bias[gn];
        #pragma unroll
        for (int i = 0; i < 4; ++i) {
            #pragma unroll
            for (int r = 0; r < 4; ++r) {
                int gm = m0 + i * 16 + rowQ * 4 + r;
                H[(size_t)gm * N2 + gn] = crelu_f(acc[i][j][r] + bv);
            }
        }
    }
}

// ---------------- K5: tail (h2 + h3, bucket-selected) ----------------
__global__ __launch_bounds__(256) void tail_kernel(
    const float* __restrict__ H,
    const int* __restrict__ bucket,
    const float* __restrict__ h2w,     // (8,32,32)
    const float* __restrict__ h2b,     // (8,32)
    const float* __restrict__ h3w,     // (8,1,32)
    const float* __restrict__ h3b,     // (8,1)
    float* __restrict__ out, int B)
{
    int s = blockIdx.x * 8 + (threadIdx.x >> 5);
    int j = threadIdx.x & 31;
    if (s >= B) return;
    int k = bucket[s];
    float h1v = H[(size_t)s * N2 + k * 32 + j];
    const float* w2 = h2w + ((k * 32 + j) * 32);
    float a = h2b[k * 32 + j];
    #pragma unroll
    for (int i = 0; i < 32; ++i) a += w2[i] * __shfl(h1v, i, 32);
    a = crelu_f(a);
    float p = a * h3w[k * 32 + j];
    #pragma unroll
    for (int off = 16; off; off >>= 1) p += __shfl_down(p, off, 32);
    if (j == 0) out[s] = p + h3b[k];
}

extern "C" void kernel_launch(void* const* d_in, const int* in_sizes, int n_in,
                              void* d_out, int out_size, void* d_ws, size_t ws_size,
                              hipStream_t stream) {
    const float* x    = (const float*)d_in[0];
    const float* ftw  = (const float*)d_in[1];
    const float* ftb  = (const float*)d_in[2];
    const float* h1w  = (const float*)d_in[3];
    const float* h1b  = (const float*)d_in[4];
    const float* h2w  = (const float*)d_in[5];
    const float* h2b  = (const float*)d_in[6];
    const float* h3w  = (const float*)d_in[7];
    const float* h3b  = (const float*)d_in[8];
    float* out = (float*)d_out;

    int B = in_sizes[0] / (2 * INF);          // 65536

    // workspace layout
    char* ws = (char*)d_ws;
    _Float16* C1    = (_Float16*)ws;                          // 2B*512*2 = 134 MB
    size_t c1_b     = (size_t)2 * B * FT * sizeof(_Float16);
    _Float16* ftw16 = (_Float16*)(ws + c1_b);                 // 512*800*2
    size_t ftw_b    = (size_t)FT * KP * sizeof(_Float16);
    _Float16* h1w16 = (_Float16*)(ws + c1_b + ftw_b);         // 256*1024*2
    size_t h1w_b    = (size_t)N2 * K2 * sizeof(_Float16);
    int* bucket     = (int*)(ws + c1_b + ftw_b + h1w_b);      // B*4
    size_t bk_b     = (size_t)B * sizeof(int);
    float* H        = (float*)(ws + c1_b + ftw_b + h1w_b + bk_b); // B*256*4

    // K2: weights
    {
        int total = FT * KP + N2 * K2;
        convert_w_kernel<<<(total + 255) / 256, 256, 0, stream>>>(ftw, h1w, ftw16, h1w16);
    }
    // K3: fused FT GEMM (+bucket)
    gemm_ft_fused<<<(2 * B / 128) * 2, 512, 0, stream>>>(x, ftw16, ftb, C1, bucket, B);
    // K4: h1 GEMM
    gemm_h1_kernel<<<B / 64, 512, 0, stream>>>(C1, h1w16, h1b, H, B);
    // K5: tail
    tail_kernel<<<(B + 7) / 8, 256, 0, stream>>>(H, bucket, h2w, h2b, h3w, h3b, out, B);
}

// Round 4
// 834.461 us; speedup vs baseline: 1.4424x; 1.4424x over previous
//
#include <hip/hip_runtime.h>
#include <stdint.h>

// NNUE bucket model R5 (2nd resubmit — R2/R3 benches were broker
// GPUAcquisitionTimeouts, no data): counted-vmcnt deep pipeline (T3+T4).
//   R4 post-mortem: A-reg prefetch spilled (WRITE_SIZE 168->1045 MB) because
//   fp32 prefetch regs lived across the MFMA block under the 128-VGPR cap;
//   and __syncthreads()' vmcnt(0) drain capped overlap at one MFMA phase.
//   R5: convert_x restored (x -> fp16 (2B,800) padded, bucket computed there
//   in exact fp32), so BOTH GEMM operands stage via global_load_lds (zero
//   VGPR cost, async). Triple-buffered LDS (72 KB, 2 blocks/CU), raw
//   s_barrier + counted s_waitcnt vmcnt(6): 3 gl_lds/wave/stage uniform,
//   stages t+1,t+2 stay in flight across barriers; tails vmcnt(3)/vmcnt(0).
//   gemm_h1 moved to BM=128 so it is structurally identical to gemm_ft.
//   Chunk-XOR source-side swizzle kept (conflicts = 0 in R3).

#define INF  770
#define XROW 1540
#define KP   800
#define FT   512
#define K2   1024
#define N2   256

typedef _Float16 half8 __attribute__((ext_vector_type(8)));
typedef _Float16 half4 __attribute__((ext_vector_type(4)));
typedef _Float16 half2v __attribute__((ext_vector_type(2)));
typedef float floatx4 __attribute__((ext_vector_type(4)));

__device__ __forceinline__ float crelu_f(float v) {
    return v < 0.f ? 0.f : (v > 1.f ? 1.f : v);
}

__device__ __forceinline__ void gl_lds16(const _Float16* g, _Float16* l) {
    __builtin_amdgcn_global_load_lds(
        (__attribute__((address_space(1))) void*)(uintptr_t)(const void*)g,
        (__attribute__((address_space(3))) void*)l,
        16, 0, 0);
}

#define VMCNT(n) asm volatile("s_waitcnt vmcnt(" #n ")" ::: "memory")
#define BAR() do { asm volatile("" ::: "memory"); \
                   __builtin_amdgcn_s_barrier(); \
                   asm volatile("" ::: "memory"); } while (0)

// ---------------- K1: convert weights ----------------
__global__ __launch_bounds__(256) void convert_w_kernel(
    const float* __restrict__ ftw, const float* __restrict__ h1w,
    _Float16* __restrict__ ftw16, _Float16* __restrict__ h1w16)
{
    int idx = blockIdx.x * 256 + threadIdx.x;
    const int FTW = FT * KP;            // 409600
    if (idx < FTW) {
        int r = idx / KP, c = idx - r * KP;
        ftw16[idx] = (_Float16)(c < INF ? ftw[r * INF + c] : 0.f);
    } else {
        int j = idx - FTW;
        if (j < N2 * K2) h1w16[j] = (_Float16)h1w[j];
    }
}

// ---------------- K2: convert x -> fp16 (2B, 800) padded + bucket ----------------
// Wave per row. x16[r][0..769] = stm row r, x16[B+r][0..769] = nstm row r,
// cols 770..799 zero. pc = sum x[:, :768] in exact fp32 (float4 j<192).
__global__ __launch_bounds__(256) void convert_x_kernel(
    const float* __restrict__ x, _Float16* __restrict__ x16,
    int* __restrict__ bucket, int B)
{
    int r = blockIdx.x * 4 + (threadIdx.x >> 6);
    int l = threadIdx.x & 63;
    const float* xr = x + (size_t)r * XROW;
    _Float16* stm = x16 + (size_t)r * KP;
    _Float16* nst = x16 + (size_t)(B + r) * KP;
    float psum = 0.f;
    for (int j = l; j < 385; j += 64) {
        floatx4 f = *(const floatx4*)(xr + j * 4);
        int c = j * 4;
        if (j < 192) psum += (f.x + f.y) + (f.z + f.w);
        if (c + 3 < INF) {                    // j <= 191: pure stm
            half4 hv = {(_Float16)f.x, (_Float16)f.y, (_Float16)f.z, (_Float16)f.w};
            *(half4*)(stm + c) = hv;
        } else if (c < INF) {                 // j == 192: straddles 770
            stm[768] = (_Float16)f.x; stm[769] = (_Float16)f.y;
            nst[0]   = (_Float16)f.z; nst[1]  = (_Float16)f.w;
        } else {                              // j >= 193: nstm, 4B-aligned
            int cc = c - INF;
            half2v h0 = {(_Float16)f.x, (_Float16)f.y};
            half2v h1 = {(_Float16)f.z, (_Float16)f.w};
            *(half2v*)(nst + cc) = h0;
            *(half2v*)(nst + cc + 2) = h1;
        }
    }
    // zero pads cols 770..799
    half2v z = {};
    if (l < 15)                *(half2v*)(stm + INF + 2 * l) = z;
    else if (l >= 16 && l < 31) *(half2v*)(nst + INF + 2 * (l - 16)) = z;
    // bucket
    #pragma unroll
    for (int off = 1; off < 64; off <<= 1) psum += __shfl_xor(psum, off, 64);
    if (l == 0) {
        int bk = (int)(psum * (8.0f / 33.0f));
        bucket[r] = bk < 0 ? 0 : (bk > 7 ? 7 : bk);
    }
}

// ---------------- K3: FT GEMM, deep-pipelined ----------------
// A = x16 (2B, 800), B = ftw16 (512, 800), C fp16 (2B, 512).
// BM=128 BN=256 BK=32, 512 thr / 8 waves (2m x 4n), NT=25.
__global__ __launch_bounds__(512, 4) void gemm_ft_p(
    const _Float16* __restrict__ A,
    const _Float16* __restrict__ Bw,
    const float* __restrict__ bias,
    _Float16* __restrict__ C)
{
    __shared__ _Float16 lsA[3][128 * 32];   // 24 KB
    __shared__ _Float16 lsB[3][256 * 32];   // 48 KB
    // XCD pairing: the 2 n-blocks of one m-tile land adjacent on one XCD so
    // the 2nd read of the A-tile (200 KB fp16) hits that L2.
    int bid = blockIdx.x;
    int xcd = bid & 7, g = bid >> 3;
    int nt = g & 1, mt = (g >> 1) * 8 + xcd;
    int m0 = mt * 128, n0 = nt * 256;
    int tid = threadIdx.x, lane = tid & 63, w = tid >> 6;
    int rm = (w & 1) * 64, rn = (w >> 1) * 64;
    int colL = lane & 15, rowQ = lane >> 4;
    int chA = rowQ ^ ((colL >> 1) & 3);

    // staging: 16B transfer idx -> (row = idx>>2, src chunk = (idx&3)^((row>>1)&3))
    int ar = tid >> 2, as_ = (tid & 3) ^ ((ar >> 1) & 3);
    const _Float16* pa = A + (size_t)(m0 + ar) * KP + as_ * 8;
    const _Float16* pb = Bw + (size_t)(n0 + ar) * KP + as_ * 8;  // q=1 row = ar+128, same chunk xor

    floatx4 acc[4][4] = {};

    auto STAGE = [&](int kt, _Float16* dA, _Float16* dB) {
        gl_lds16(pa + kt * 32, dA + tid * 8);
        gl_lds16(pb + kt * 32, dB + tid * 8);
        gl_lds16(pb + 128 * KP + kt * 32, dB + (512 + tid) * 8);
    };
    auto COMPUTE = [&](const _Float16* bA, const _Float16* bB) {
        half8 af[4], bf[4];
        #pragma unroll
        for (int i = 0; i < 4; ++i)
            af[i] = *(const half8*)(bA + (rm + i * 16 + colL) * 32 + chA * 8);
        #pragma unroll
        for (int j = 0; j < 4; ++j)
            bf[j] = *(const half8*)(bB + (rn + j * 16 + colL) * 32 + chA * 8);
        __builtin_amdgcn_s_setprio(1);
        #pragma unroll
        for (int i = 0; i < 4; ++i)
            #pragma unroll
            for (int j = 0; j < 4; ++j)
                acc[i][j] = __builtin_amdgcn_mfma_f32_16x16x32_f16(af[i], bf[j], acc[i][j], 0, 0, 0);
        __builtin_amdgcn_s_setprio(0);
    };

    _Float16 *cA0 = lsA[0], *cA1 = lsA[1], *cA2 = lsA[2];
    _Float16 *cB0 = lsB[0], *cB1 = lsB[1], *cB2 = lsB[2];

    STAGE(0, cA0, cB0);
    STAGE(1, cA1, cB1);

    // main: NT=25 -> t = 0..22 stage t+2; wait = 2 stages in flight * 3 = 6
    for (int t = 0; t < 23; ++t) {
        STAGE(t + 2, cA2, cB2);
        VMCNT(6);
        BAR();
        COMPUTE(cA0, cB0);
        BAR();
        _Float16* tA = cA0; cA0 = cA1; cA1 = cA2; cA2 = tA;
        _Float16* tB = cB0; cB0 = cB1; cB1 = cB2; cB2 = tB;
    }
    // t = 23: one stage (24) newer -> vmcnt(3)
    VMCNT(3);
    BAR();
    COMPUTE(cA0, cB0);
    BAR();
    { _Float16* tA = cA0; cA0 = cA1; cA1 = cA2; cA2 = tA;
      _Float16* tB = cB0; cB0 = cB1; cB1 = cB2; cB2 = tB; }
    // t = 24: nothing newer
    VMCNT(0);
    BAR();
    COMPUTE(cA0, cB0);

    // epilogue
    #pragma unroll
    for (int j = 0; j < 4; ++j) {
        int gn = n0 + rn + j * 16 + colL;
        float bv = bias[gn];
        #pragma unroll
        for (int i = 0; i < 4; ++i) {
            #pragma unroll
            for (int r = 0; r < 4; ++r) {
                int gm = m0 + rm + i * 16 + rowQ * 4 + r;
                C[(size_t)gm * FT + gn] = (_Float16)crelu_f(acc[i][j][r] + bv);
            }
        }
    }
}

// ---------------- K4: h1 GEMM, deep-pipelined (BM=128, full-N) ----------------
// A = combined = [C1[m] | C1[B+m]] (K=1024), B = h1w16 (256, 1024), H fp32.
__global__ __launch_bounds__(512, 4) void gemm_h1_p(
    const _Float16* __restrict__ C1,
    const _Float16* __restrict__ Bw,
    const float* __restrict__ bias,
    float* __restrict__ H,
    int B)
{
    __shared__ _Float16 lsA[3][128 * 32];   // 24 KB
    __shared__ _Float16 lsB[3][256 * 32];   // 48 KB
    int m0 = blockIdx.x * 128;
    int tid = threadIdx.x, lane = tid & 63, w = tid >> 6;
    int rm = (w & 1) * 64, rn = (w >> 1) * 64;
    int colL = lane & 15, rowQ = lane >> 4;
    int chA = rowQ ^ ((colL >> 1) & 3);

    int ar = tid >> 2, as_ = (tid & 3) ^ ((ar >> 1) & 3);
    const _Float16* pa  = C1 + (size_t)(m0 + ar) * FT + as_ * 8;          // k < 512
    const _Float16* paH = C1 + (size_t)(B + m0 + ar) * FT + as_ * 8;      // k >= 512
    const _Float16* pb  = Bw + (size_t)ar * K2 + as_ * 8;

    floatx4 acc[4][4] = {};

    auto STAGE = [&](int kt, _Float16* dA, _Float16* dB) {
        const _Float16* a = (kt < 16) ? (pa + kt * 32) : (paH + (kt - 16) * 32);
        gl_lds16(a, dA + tid * 8);
        gl_lds16(pb + kt * 32, dB + tid * 8);
        gl_lds16(pb + 128 * K2 + kt * 32, dB + (512 + tid) * 8);
    };
    auto COMPUTE = [&](const _Float16* bA, const _Float16* bB) {
        half8 af[4], bf[4];
        #pragma unroll
        for (int i = 0; i < 4; ++i)
            af[i] = *(const half8*)(bA + (rm + i * 16 + colL) * 32 + chA * 8);
        #pragma unroll
        for (int j = 0; j < 4; ++j)
            bf[j] = *(const half8*)(bB + (rn + j * 16 + colL) * 32 + chA * 8);
        __builtin_amdgcn_s_setprio(1);
        #pragma unroll
        for (int i = 0; i < 4; ++i)
            #pragma unroll
            for (int j = 0; j < 4; ++j)
                acc[i][j] = __builtin_amdgcn_mfma_f32_16x16x32_f16(af[i], bf[j], acc[i][j], 0, 0, 0);
        __builtin_amdgcn_s_setprio(0);
    };

    _Float16 *cA0 = lsA[0], *cA1 = lsA[1], *cA2 = lsA[2];
    _Float16 *cB0 = lsB[0], *cB1 = lsB[1], *cB2 = lsB[2];

    STAGE(0, cA0, cB0);
    STAGE(1, cA1, cB1);

    // NT=32 -> main t = 0..29
    for (int t = 0; t < 30; ++t) {
        STAGE(t + 2, cA2, cB2);
        VMCNT(6);
        BAR();
        COMPUTE(cA0, cB0);
        BAR();
        _Float16* tA = cA0; cA0 = cA1; cA1 = cA2; cA2 = tA;
        _Float16* tB = cB0; cB0 = cB1; cB1 = cB2; cB2 = tB;
    }
    VMCNT(3);
    BAR();
    COMPUTE(cA0, cB0);
    BAR();
    { _Float16* tA = cA0; cA0 = cA1; cA1 = cA2; cA2 = tA;
      _Float16* tB = cB0; cB0 = cB1; cB1 = cB2; cB2 = tB; }
    VMCNT(0);
    BAR();
    COMPUTE(cA0, cB0);

    #pragma unroll
    for (int j = 0; j < 4; ++j) {
        int gn = rn + j * 16 + colL;
        float bv = bias[gn];
        #pragma unroll
        for (int i = 0; i < 4; ++i) {
            #pragma unroll
            for (int r = 0; r < 4; ++r) {
                int gm = m0 + rm + i * 16 + rowQ * 4 + r;
                H[(size_t)gm * N2 + gn] = crelu_f(acc[i][j][r] + bv);
            }
        }
    }
}

// ---------------- K5: tail (h2 + h3, bucket-selected) ----------------
__global__ __launch_bounds__(256) void tail_kernel(
    const float* __restrict__ H,
    const int* __restrict__ bucket,
    const float* __restrict__ h2w,     // (8,32,32)
    const float* __restrict__ h2b,     // (8,32)
    const float* __restrict__ h3w,     // (8,1,32)
    const float* __restrict__ h3b,     // (8,1)
    float* __restrict__ out, int B)
{
    int s = blockIdx.x * 8 + (threadIdx.x >> 5);
    int j = threadIdx.x & 31;
    if (s >= B) return;
    int k = bucket[s];
    float h1v = H[(size_t)s * N2 + k * 32 + j];
    const float* w2 = h2w + ((k * 32 + j) * 32);
    float a = h2b[k * 32 + j];
    #pragma unroll
    for (int i = 0; i < 32; ++i) a += w2[i] * __shfl(h1v, i, 32);
    a = crelu_f(a);
    float p = a * h3w[k * 32 + j];
    #pragma unroll
    for (int off = 16; off; off >>= 1) p += __shfl_down(p, off, 32);
    if (j == 0) out[s] = p + h3b[k];
}

extern "C" void kernel_launch(void* const* d_in, const int* in_sizes, int n_in,
                              void* d_out, int out_size, void* d_ws, size_t ws_size,
                              hipStream_t stream) {
    const float* x    = (const float*)d_in[0];
    const float* ftw  = (const float*)d_in[1];
    const float* ftb  = (const float*)d_in[2];
    const float* h1w  = (const float*)d_in[3];
    const float* h1b  = (const float*)d_in[4];
    const float* h2w  = (const float*)d_in[5];
    const float* h2b  = (const float*)d_in[6];
    const float* h3w  = (const float*)d_in[7];
    const float* h3b  = (const float*)d_in[8];
    float* out = (float*)d_out;

    int B = in_sizes[0] / (2 * INF);          // 65536

    // workspace layout (~413 MB total)
    char* ws = (char*)d_ws;
    _Float16* C1    = (_Float16*)ws;                          // 2B*512*2 = 134 MB
    size_t c1_b     = (size_t)2 * B * FT * sizeof(_Float16);
    _Float16* ftw16 = (_Float16*)(ws + c1_b);                 // 512*800*2
    size_t ftw_b    = (size_t)FT * KP * sizeof(_Float16);
    _Float16* h1w16 = (_Float16*)(ws + c1_b + ftw_b);         // 256*1024*2
    size_t h1w_b    = (size_t)N2 * K2 * sizeof(_Float16);
    int* bucket     = (int*)(ws + c1_b + ftw_b + h1w_b);      // B*4
    size_t bk_b     = (size_t)B * sizeof(int);
    float* H        = (float*)(ws + c1_b + ftw_b + h1w_b + bk_b); // B*256*4 = 67 MB
    size_t H_b      = (size_t)B * N2 * sizeof(float);
    _Float16* x16   = (_Float16*)(ws + c1_b + ftw_b + h1w_b + bk_b + H_b); // 2B*800*2 = 210 MB

    // K1: weights
    {
        int total = FT * KP + N2 * K2;
        convert_w_kernel<<<(total + 255) / 256, 256, 0, stream>>>(ftw, h1w, ftw16, h1w16);
    }
    // K2: x -> fp16 + bucket
    convert_x_kernel<<<B / 4, 256, 0, stream>>>(x, x16, bucket, B);
    // K3: FT GEMM
    gemm_ft_p<<<(2 * B / 128) * 2, 512, 0, stream>>>(x16, ftw16, ftb, C1);
    // K4: h1 GEMM
    gemm_h1_p<<<B / 128, 512, 0, stream>>>(C1, h1w16, h1b, H, B);
    // K5: tail
    tail_kernel<<<(B + 7) / 8, 256, 0, stream>>>(H, bucket, h2w, h2b, h3w, h3b, out, B);
}